// Round 2
// baseline (928.650 us; speedup 1.0000x reference)
//
#include <hip/hip_runtime.h>
#include <hip/hip_bf16.h>

// ---------------------------------------------------------------------------
// TGSA round 2: vectorized LDS-staged GEMM epilogues + mask fused into G4.
//   dot = x.tq = img.tq + g_gcn*(h.u + b2.tq), u = W2 @ tq
//   img.tq accumulated in prep_x (atomicAdd), h.u in scale_k.
// ---------------------------------------------------------------------------

#define BATCH 256
#define NTOK  196
#define PN    256
#define DIMG  768
#define DTXT  512
#define MROWS (BATCH*NTOK)
#define LN_EPS 1e-5f

typedef __hip_bfloat16 bf16_t;
typedef __hip_bfloat162 bf2_t;
typedef __bf16 bf16x8 __attribute__((ext_vector_type(8)));
typedef float  f32x4  __attribute__((ext_vector_type(4)));

typedef const __attribute__((address_space(1))) void gvoid_t;
typedef __attribute__((address_space(3))) void lvoid_t;

__device__ __forceinline__ float gelu_f(float x){
    return 0.5f * x * (1.0f + erff(x * 0.70710678118654752440f));
}

// --- prep: cast x to bf16 (padded) + x^T (padded) + partial img.tq dots ---
__global__ void prep_x(const float* __restrict__ img, const float* __restrict__ tq,
                       bf16_t* __restrict__ xb, bf16_t* __restrict__ xt,
                       float* __restrict__ dimg){
    __shared__ float tile[32][33];
    const int b  = blockIdx.z;
    const int m0 = blockIdx.y * 32;
    const int d0 = blockIdx.x * 32;
    const int tx = threadIdx.x, ty = threadIdx.y;
    const float tqv = tq[(size_t)b*DIMG + d0 + tx];
    #pragma unroll
    for (int i = 0; i < 4; i++){
        const int m = m0 + ty + i*8;
        float v = 0.f;
        if (m < NTOK) v = img[((size_t)b*197 + 1 + m)*DIMG + d0 + tx];
        tile[ty + i*8][tx] = v;
        xb[((size_t)b*PN + m)*DIMG + d0 + tx] = __float2bfloat16(v);
        float p = v * tqv;
        #pragma unroll
        for (int o = 1; o < 32; o <<= 1) p += __shfl_xor(p, o);
        if (tx == 0 && m < NTOK) atomicAdd(&dimg[(size_t)b*NTOK + m], p);
    }
    __syncthreads();
    #pragma unroll
    for (int i = 0; i < 4; i++){
        const int d = d0 + ty + i*8;
        xt[((size_t)b*DIMG + d)*PN + m0 + tx] = __float2bfloat16(tile[tx][ty + i*8]);
    }
}

// --- prep: transpose+cast 768x768 weight --------------------------------
__global__ void prep_w(const float* __restrict__ w, bf16_t* __restrict__ wt){
    __shared__ float tile[32][33];
    const int r0 = blockIdx.y * 32, c0 = blockIdx.x * 32;
    const int tx = threadIdx.x, ty = threadIdx.y;
    #pragma unroll
    for (int i = 0; i < 4; i++)
        tile[ty + i*8][tx] = w[(size_t)(r0 + ty + i*8)*DIMG + c0 + tx];
    __syncthreads();
    #pragma unroll
    for (int i = 0; i < 4; i++)
        wt[(size_t)(c0 + ty + i*8)*DIMG + r0 + tx] = __float2bfloat16(tile[tx][ty + i*8]);
}

// --- cls passthrough ------------------------------------------------------
__global__ void cls_copy(const float* __restrict__ img, float* __restrict__ out){
    const int i = blockIdx.x * 256 + threadIdx.x;
    const int b = i / DIMG, d = i - b*DIMG;
    out[((size_t)b*197)*DIMG + d] = img[((size_t)b*197)*DIMG + d];
}

// --- text branch ----------------------------------------------------------
__global__ void txt_fc1(const float* __restrict__ text, const float* __restrict__ w,
                        const float* __restrict__ bias, float* __restrict__ h){
    __shared__ float ts[DTXT];
    const int b = blockIdx.y;
    const int n = blockIdx.x * 256 + threadIdx.x;
    for (int k = threadIdx.x; k < DTXT; k += 256) ts[k] = text[(size_t)b*DTXT + k];
    __syncthreads();
    float acc = 0.f;
    for (int k = 0; k < DTXT; k++) acc = fmaf(ts[k], w[(size_t)k*DIMG + n], acc);
    h[(size_t)b*DIMG + n] = gelu_f(acc + bias[n]);
}

__global__ void txt_fc2(const float* __restrict__ h, const float* __restrict__ w,
                        const float* __restrict__ bias, float* __restrict__ tq){
    __shared__ float ts[DIMG];
    const int b = blockIdx.y;
    const int n = blockIdx.x * 256 + threadIdx.x;
    for (int k = threadIdx.x; k < DIMG; k += 256) ts[k] = h[(size_t)b*DIMG + k];
    __syncthreads();
    float acc = 0.f;
    for (int k = 0; k < DIMG; k++) acc = fmaf(ts[k], w[(size_t)k*DIMG + n], acc);
    tq[(size_t)b*DIMG + n] = acc + bias[n];
}

__global__ void txt_ln(float* __restrict__ tq, const float* __restrict__ lw,
                       const float* __restrict__ lb){
    __shared__ float red[4];
    const int b = blockIdx.x, t = threadIdx.x;
    const int wv = t >> 6, lane = t & 63;
    float x[3];
    #pragma unroll
    for (int i = 0; i < 3; i++) x[i] = tq[(size_t)b*DIMG + t + i*256];
    float s = x[0] + x[1] + x[2];
    #pragma unroll
    for (int o = 1; o < 64; o <<= 1) s += __shfl_xor(s, o);
    if (lane == 0) red[wv] = s;
    __syncthreads();
    const float mu = (red[0]+red[1]+red[2]+red[3]) * (1.f/768.f);
    float q = 0.f;
    #pragma unroll
    for (int i = 0; i < 3; i++){ const float d = x[i]-mu; q = fmaf(d, d, q); }
    #pragma unroll
    for (int o = 1; o < 64; o <<= 1) q += __shfl_xor(q, o);
    __syncthreads();
    if (lane == 0) red[wv] = q;
    __syncthreads();
    const float var = (red[0]+red[1]+red[2]+red[3]) * (1.f/768.f);
    const float inv = rsqrtf(var + LN_EPS);
    #pragma unroll
    for (int i = 0; i < 3; i++){
        const int d = t + i*256;
        tq[(size_t)b*DIMG + d] = (x[i]-mu)*inv*lw[d] + lb[d];
    }
}

// --- u[b] = W2 @ tq[b]  (u[n] = sum_c W2[n][c] tq[c] = sum_c w2T[c][n] tq[c])
__global__ void calc_u(const float* __restrict__ tq, const bf16_t* __restrict__ w2T,
                       float* __restrict__ u){
    __shared__ float ts[DIMG];
    const int b = blockIdx.y;
    const int n = blockIdx.x * 256 + threadIdx.x;
    for (int k = threadIdx.x; k < DIMG; k += 256) ts[k] = tq[(size_t)b*DIMG + k];
    __syncthreads();
    float acc = 0.f;
    for (int k = 0; k < DIMG; k++)
        acc = fmaf(ts[k], __bfloat162float(w2T[(size_t)k*DIMG + n]), acc);
    u[(size_t)b*DIMG + n] = acc;
}

// --- softmax over rows of S ----------------------------------------------
__global__ void softmax_k(const float* __restrict__ S, bf16_t* __restrict__ A){
    const int gr = blockIdx.x * 4 + (threadIdx.x >> 6);
    const int lane = threadIdx.x & 63;
    if (gr >= MROWS) return;
    const int b = gr / NTOK, m = gr - b*NTOK;
    const float* row = S + ((size_t)b*PN + m)*PN;
    const float scale = 0.03608439182435161256f;   // 1/sqrt(768)
    float v[4]; float mx = -1e30f;
    #pragma unroll
    for (int i = 0; i < 4; i++){
        const int n = lane + i*64;
        const float val = (n < NTOK) ? row[n]*scale : -1e30f;
        v[i] = val; mx = fmaxf(mx, val);
    }
    #pragma unroll
    for (int o = 1; o < 64; o <<= 1) mx = fmaxf(mx, __shfl_xor(mx, o));
    float sum = 0.f;
    #pragma unroll
    for (int i = 0; i < 4; i++){ v[i] = expf(v[i] - mx); sum += v[i]; }
    #pragma unroll
    for (int o = 1; o < 64; o <<= 1) sum += __shfl_xor(sum, o);
    const float inv = 1.f / sum;
    bf16_t* orow = A + ((size_t)b*PN + m)*PN;
    #pragma unroll
    for (int i = 0; i < 4; i++) orow[lane + i*64] = __float2bfloat16(v[i]*inv);
}

// --- scale[row] = 1 + gamma*sigmoid(dimg[row] + g_gcn*(h.u + b2.tq)) -----
__global__ void scale_k(const bf16_t* __restrict__ h, const float* __restrict__ u,
                        const float* __restrict__ dimg, const float* __restrict__ b2,
                        const float* __restrict__ tq, const float* __restrict__ ggcn,
                        const float* __restrict__ gam, float* __restrict__ scale){
    const int gr = blockIdx.x * 4 + (threadIdx.x >> 6);
    const int lane = threadIdx.x & 63;
    if (gr >= MROWS) return;
    const int b = gr / NTOK;
    const bf16_t* hr = h + (size_t)gr*DIMG;
    const float* ub = u + (size_t)b*DIMG;
    const float* tb = tq + (size_t)b*DIMG;
    float s = 0.f;
    #pragma unroll
    for (int i = 0; i < 6; i++){
        const int d = i*128 + lane*2;
        const bf2_t hv = *(const bf2_t*)(hr + d);
        const float2 uv = *(const float2*)(ub + d);
        const float2 bv = *(const float2*)(b2 + d);
        const float2 tv = *(const float2*)(tb + d);
        s = fmaf(__bfloat162float(hv.x), uv.x, s);
        s = fmaf(__bfloat162float(hv.y), uv.y, s);
        s = fmaf(bv.x, tv.x, s);
        s = fmaf(bv.y, tv.y, s);
    }
    #pragma unroll
    for (int o = 1; o < 64; o <<= 1) s += __shfl_xor(s, o);
    const float dot = dimg[gr] + ggcn[0]*s;
    if (lane == 0)
        scale[gr] = 1.f + gam[0] / (1.f + expf(-dot));
}

// --- MFMA GEMM with LDS-staged vectorized epilogue -----------------------
// MODE 0: fp32 S (batched)          MODE 1: bf16 msg (row<196, dense remap)
// MODE 2: bf16 h = gelu(C+bias)     MODE 3: fp32 out = (res + g*(C+bias))*scale
template<int MODE>
__global__ __launch_bounds__(256) void gemm_bt(
    const bf16_t* __restrict__ Aall, const bf16_t* __restrict__ Btall,
    int lda, int ldb, int K,
    long long strideA, long long strideB,
    float* __restrict__ outF, bf16_t* __restrict__ outB,
    const float* __restrict__ bias, const float* __restrict__ res,
    const float* __restrict__ gscal, const float* __restrict__ scale)
{
    __shared__ __align__(16) union {
        struct { bf16_t a[128*32]; bf16_t b[128*32]; } s;
        float ep[32*132];                      // 132-pad: 2-way banks only
    } sm;
    const int b  = blockIdx.z;
    const int m0 = blockIdx.y * 128;
    const int n0 = blockIdx.x * 128;
    const bf16_t* Ab = Aall + (long long)b * strideA;
    const bf16_t* Bb = Btall + (long long)b * strideB;

    const int t    = threadIdx.x;
    const int lane = t & 63;
    const int wave = t >> 6;
    const int wm   = (wave & 1) * 64;
    const int wn   = (wave >> 1) * 64;
    const int fr   = lane & 15;
    const int quad = lane >> 4;

    f32x4 acc[4][4];
    #pragma unroll
    for (int i = 0; i < 4; i++)
        #pragma unroll
        for (int j = 0; j < 4; j++)
            acc[i][j] = (f32x4){0.f, 0.f, 0.f, 0.f};

    const int lin0 = t, lin1 = t + 256;
    const int r0 = lin0 >> 2, s0 = (lin0 & 3) * 8;
    const int r1 = lin1 >> 2, s1 = (lin1 & 3) * 8;

    for (int k0 = 0; k0 < K; k0 += 32){
        __syncthreads();
        __builtin_amdgcn_global_load_lds((gvoid_t*)(Ab + (long long)(m0+r0)*lda + k0 + s0),
                                         (lvoid_t*)(sm.s.a + lin0*8), 16, 0, 0);
        __builtin_amdgcn_global_load_lds((gvoid_t*)(Ab + (long long)(m0+r1)*lda + k0 + s1),
                                         (lvoid_t*)(sm.s.a + lin1*8), 16, 0, 0);
        __builtin_amdgcn_global_load_lds((gvoid_t*)(Bb + (long long)(n0+r0)*ldb + k0 + s0),
                                         (lvoid_t*)(sm.s.b + lin0*8), 16, 0, 0);
        __builtin_amdgcn_global_load_lds((gvoid_t*)(Bb + (long long)(n0+r1)*ldb + k0 + s1),
                                         (lvoid_t*)(sm.s.b + lin1*8), 16, 0, 0);
        __syncthreads();
        bf16x8 fa[4], fb[4];
        #pragma unroll
        for (int i = 0; i < 4; i++){
            fa[i] = *(const bf16x8*)(sm.s.a + (wm + i*16 + fr)*32 + quad*8);
            fb[i] = *(const bf16x8*)(sm.s.b + (wn + i*16 + fr)*32 + quad*8);
        }
        #pragma unroll
        for (int i = 0; i < 4; i++)
            #pragma unroll
            for (int j = 0; j < 4; j++)
                acc[i][j] = __builtin_amdgcn_mfma_f32_16x16x32_bf16(fa[i], fb[j], acc[i][j], 0, 0, 0);
    }

    // --- epilogue: 4 chunks of 32 rows through LDS, coalesced stores ---
    const float g = (MODE == 3) ? gscal[0] : 0.f;
    const int lr = t >> 3;            // 0..31 local row in chunk
    const int cs = (t & 7) * 16;      // col segment start
    #pragma unroll
    for (int c = 0; c < 4; c++){
        __syncthreads();
        if ((wm == 0) == (c < 2)){
            const int ib = (c & 1) * 2;
            #pragma unroll
            for (int ii = 0; ii < 2; ii++)
                #pragma unroll
                for (int j = 0; j < 4; j++)
                    #pragma unroll
                    for (int r = 0; r < 4; r++)
                        sm.ep[(ii*16 + quad*4 + r)*132 + wn + j*16 + fr] = acc[ib+ii][j][r];
        }
        __syncthreads();
        const int grow = m0 + c*32 + lr;
        float4 v[4];
        const float4* vp = (const float4*)(sm.ep + lr*132 + cs);
        #pragma unroll
        for (int k = 0; k < 4; k++) v[k] = vp[k];

        if (MODE == 0){
            float4* dp = (float4*)(outF + ((long long)b*PN + grow)*PN + n0 + cs);
            #pragma unroll
            for (int k = 0; k < 4; k++) dp[k] = v[k];
        } else if (MODE == 1){
            if (grow < NTOK){
                bf16_t tmp[16];
                #pragma unroll
                for (int k = 0; k < 4; k++){
                    tmp[4*k+0] = __float2bfloat16(v[k].x);
                    tmp[4*k+1] = __float2bfloat16(v[k].y);
                    tmp[4*k+2] = __float2bfloat16(v[k].z);
                    tmp[4*k+3] = __float2bfloat16(v[k].w);
                }
                float4* dp = (float4*)(outB + ((long long)b*NTOK + grow)*DIMG + n0 + cs);
                dp[0] = ((float4*)tmp)[0];
                dp[1] = ((float4*)tmp)[1];
            }
        } else if (MODE == 2){
            const float4* bp = (const float4*)(bias + n0 + cs);
            bf16_t tmp[16];
            #pragma unroll
            for (int k = 0; k < 4; k++){
                const float4 bv = bp[k];
                tmp[4*k+0] = __float2bfloat16(gelu_f(v[k].x + bv.x));
                tmp[4*k+1] = __float2bfloat16(gelu_f(v[k].y + bv.y));
                tmp[4*k+2] = __float2bfloat16(gelu_f(v[k].z + bv.z));
                tmp[4*k+3] = __float2bfloat16(gelu_f(v[k].w + bv.w));
            }
            float4* dp = (float4*)(outB + (long long)grow*DIMG + n0 + cs);
            dp[0] = ((float4*)tmp)[0];
            dp[1] = ((float4*)tmp)[1];
        } else {
            const int bb = grow / NTOK;
            const int nn = grow - bb*NTOK;
            const long long off = ((long long)bb*197 + 1 + nn)*DIMG + n0 + cs;
            const float sc = scale[grow];
            const float4* bp = (const float4*)(bias + n0 + cs);
            const float4* rp = (const float4*)(res + off);
            float4* dp = (float4*)(outF + off);
            #pragma unroll
            for (int k = 0; k < 4; k++){
                const float4 bv = bp[k];
                const float4 rv = rp[k];
                float4 o;
                o.x = (rv.x + g*(v[k].x + bv.x)) * sc;
                o.y = (rv.y + g*(v[k].y + bv.y)) * sc;
                o.z = (rv.z + g*(v[k].z + bv.z)) * sc;
                o.w = (rv.w + g*(v[k].w + bv.w)) * sc;
                dp[k] = o;
            }
        }
    }
}

extern "C" void kernel_launch(void* const* d_in, const int* in_sizes, int n_in,
                              void* d_out, int out_size, void* d_ws, size_t ws_size,
                              hipStream_t stream){
    (void)in_sizes; (void)n_in; (void)out_size;
    const float* img  = (const float*)d_in[0];
    const float* text = (const float*)d_in[1];
    const float* w1m  = (const float*)d_in[2];
    const float* b1m  = (const float*)d_in[3];
    const float* w2m  = (const float*)d_in[4];
    const float* b2m  = (const float*)d_in[5];
    const float* ggcn = (const float*)d_in[6];
    const float* w1t  = (const float*)d_in[7];
    const float* b1t  = (const float*)d_in[8];
    const float* w2t  = (const float*)d_in[9];
    const float* b2t  = (const float*)d_in[10];
    const float* lnw  = (const float*)d_in[11];
    const float* lnb  = (const float*)d_in[12];
    const float* gam  = (const float*)d_in[13];
    float* out = (float*)d_out;

    char* p = (char*)d_ws;
    auto alloc = [&](size_t n){ void* r = (void*)p; p += (n + 255) & ~(size_t)255; return r; };
    bf16_t* x_bf   = (bf16_t*)alloc((size_t)BATCH*PN*DIMG*2);
    bf16_t* xT_bf  = (bf16_t*)alloc((size_t)BATCH*DIMG*PN*2);
    float*  S      = (float*) alloc((size_t)BATCH*PN*PN*4);
    bf16_t* A_bf   = (bf16_t*)alloc((size_t)BATCH*PN*PN*2);
    bf16_t* msg_bf = (bf16_t*)alloc((size_t)MROWS*DIMG*2);
    bf16_t* h_bf   = (bf16_t*)alloc((size_t)MROWS*DIMG*2);
    bf16_t* w1T    = (bf16_t*)alloc((size_t)DIMG*DIMG*2);
    bf16_t* w2T    = (bf16_t*)alloc((size_t)DIMG*DIMG*2);
    float*  htxt   = (float*) alloc((size_t)BATCH*DIMG*4);
    float*  tq     = (float*) alloc((size_t)BATCH*DIMG*4);
    float*  u      = (float*) alloc((size_t)BATCH*DIMG*4);
    float*  dimg   = (float*) alloc((size_t)MROWS*4);
    float*  scl    = (float*) alloc((size_t)MROWS*4);
    if ((size_t)(p - (char*)d_ws) > ws_size) return;

    hipMemsetAsync(dimg, 0, (size_t)MROWS*4, stream);

    // text branch first (prep_x consumes tq)
    txt_fc1<<<dim3(3, BATCH), dim3(256), 0, stream>>>(text, w1t, b1t, htxt);
    txt_fc2<<<dim3(3, BATCH), dim3(256), 0, stream>>>(htxt, w2t, b2t, tq);
    txt_ln<<<dim3(BATCH), dim3(256), 0, stream>>>(tq, lnw, lnb);

    prep_w<<<dim3(24, 24), dim3(32, 8), 0, stream>>>(w1m, w1T);
    prep_w<<<dim3(24, 24), dim3(32, 8), 0, stream>>>(w2m, w2T);
    calc_u<<<dim3(3, BATCH), dim3(256), 0, stream>>>(tq, w2T, u);
    prep_x<<<dim3(24, 8, BATCH), dim3(32, 8), 0, stream>>>(img, tq, x_bf, xT_bf, dimg);
    cls_copy<<<dim3(768), dim3(256), 0, stream>>>(img, out);

    // G1: S = X X^T (batched)
    gemm_bt<0><<<dim3(2, 2, BATCH), dim3(256), 0, stream>>>(
        x_bf, x_bf, DIMG, DIMG, DIMG,
        (long long)PN*DIMG, (long long)PN*DIMG, S, nullptr, nullptr, nullptr, nullptr, nullptr);
    softmax_k<<<dim3(MROWS/4), dim3(256), 0, stream>>>(S, A_bf);
    // G2: msg = A X
    gemm_bt<1><<<dim3(6, 2, BATCH), dim3(256), 0, stream>>>(
        A_bf, xT_bf, PN, PN, PN,
        (long long)PN*PN, (long long)DIMG*PN, nullptr, msg_bf, nullptr, nullptr, nullptr, nullptr);
    // G3: h = gelu(msg @ w1 + b1)
    gemm_bt<2><<<dim3(6, 392, 1), dim3(256), 0, stream>>>(
        msg_bf, w1T, DIMG, DIMG, DIMG,
        0, 0, nullptr, h_bf, b1m, nullptr, nullptr, nullptr);
    // scale = 1 + gam*sigmoid(img.tq + g*(h.u + b2.tq))
    scale_k<<<dim3(MROWS/4), dim3(256), 0, stream>>>(h_bf, u, dimg, b2m, tq, ggcn, gam, scl);
    // G4: out rows = (img + g*(h @ w2 + b2)) * scale
    gemm_bt<3><<<dim3(6, 392, 1), dim3(256), 0, stream>>>(
        h_bf, w2T, DIMG, DIMG, DIMG,
        0, 0, out, nullptr, b2m, img, ggcn, scl);
}

// Round 3
// 809.171 us; speedup vs baseline: 1.1477x; 1.1477x over previous
//
#include <hip/hip_runtime.h>
#include <hip/hip_bf16.h>

// ---------------------------------------------------------------------------
// TGSA round 3: flash-fused attention (S=XX^T -> softmax -> P@X in one
// kernel, S/A never hit HBM), atomic-free prep, mask stays fused in G4.
// ---------------------------------------------------------------------------

#define BATCH 256
#define NTOK  196
#define PN    256
#define DIMG  768
#define DTXT  512
#define MROWS (BATCH*NTOK)
#define LN_EPS 1e-5f
#define LDP   232          // P leading dim (bf16), covers K-pad 224
#define FK    224          // PV K padded (7*32 >= 196)

typedef __hip_bfloat16 bf16_t;
typedef __hip_bfloat162 bf2_t;
typedef __bf16 bf16x8 __attribute__((ext_vector_type(8)));
typedef float  f32x4  __attribute__((ext_vector_type(4)));

typedef const __attribute__((address_space(1))) void gvoid_t;
typedef __attribute__((address_space(3))) void lvoid_t;

__device__ __forceinline__ float gelu_f(float x){
    return 0.5f * x * (1.0f + erff(x * 0.70710678118654752440f));
}

// --- prep: wave-per-row cast img->xb (padded, zeros) + dimg = img.tq -----
__global__ void prep_row(const float* __restrict__ img, const float* __restrict__ tq,
                         bf16_t* __restrict__ xb, float* __restrict__ dimg){
    const int gr = blockIdx.x * 4 + (threadIdx.x >> 6);
    const int lane = threadIdx.x & 63;
    const int b = gr >> 8, m = gr & 255;
    bf16_t* xrow = xb + ((size_t)b*PN + m)*DIMG;
    if (m < NTOK){
        const float* irow = img + ((size_t)b*197 + 1 + m)*DIMG;
        const float* trow = tq + (size_t)b*DIMG;
        float dot = 0.f;
        #pragma unroll
        for (int i = 0; i < 3; i++){
            const float4 v = *(const float4*)(irow + lane*4 + i*256);
            const float4 tv = *(const float4*)(trow + lane*4 + i*256);
            dot = fmaf(v.x, tv.x, dot); dot = fmaf(v.y, tv.y, dot);
            dot = fmaf(v.z, tv.z, dot); dot = fmaf(v.w, tv.w, dot);
            union { bf16_t h[4]; uint2 u; } tmp;
            tmp.h[0] = __float2bfloat16(v.x); tmp.h[1] = __float2bfloat16(v.y);
            tmp.h[2] = __float2bfloat16(v.z); tmp.h[3] = __float2bfloat16(v.w);
            *(uint2*)(xrow + lane*4 + i*256) = tmp.u;
        }
        #pragma unroll
        for (int o = 1; o < 64; o <<= 1) dot += __shfl_xor(dot, o);
        if (lane == 0) dimg[(size_t)b*NTOK + m] = dot;
    } else {
        const uint2 z = {0u, 0u};
        #pragma unroll
        for (int i = 0; i < 3; i++)
            *(uint2*)(xrow + lane*4 + i*256) = z;
    }
}

// --- prep: bf16 transpose xb[b][m][d] -> xt[b][d][m], 64x64 tiles --------
__global__ void prep_xt(const bf16_t* __restrict__ xb, bf16_t* __restrict__ xt){
    __shared__ unsigned short tile[64*66];
    const int b  = blockIdx.z;
    const int m0 = blockIdx.y * 64;
    const int d0 = blockIdx.x * 64;
    const int tx = threadIdx.x, ty = threadIdx.y;
    const unsigned short* src = (const unsigned short*)xb;
    unsigned short* dst = (unsigned short*)xt;
    #pragma unroll
    for (int i = 0; i < 8; i++){
        const int ml = ty + i*8;
        const unsigned v = *(const unsigned*)(src + ((size_t)b*PN + m0 + ml)*DIMG + d0 + tx*2);
        *(unsigned*)(tile + ml*66 + tx*2) = v;
    }
    __syncthreads();
    #pragma unroll
    for (int i = 0; i < 8; i++){
        const int dl = ty + i*8;
        const unsigned a = tile[(tx*2    )*66 + dl];
        const unsigned c = tile[(tx*2 + 1)*66 + dl];
        *(unsigned*)(dst + ((size_t)b*DIMG + d0 + dl)*PN + m0 + tx*2) = a | (c << 16);
    }
}

// --- cls passthrough ------------------------------------------------------
__global__ void cls_copy(const float* __restrict__ img, float* __restrict__ out){
    const int i = blockIdx.x * 256 + threadIdx.x;
    const int b = i / DIMG, d = i - b*DIMG;
    out[((size_t)b*197)*DIMG + d] = img[((size_t)b*197)*DIMG + d];
}

// --- text branch ----------------------------------------------------------
__global__ void txt_fc1(const float* __restrict__ text, const float* __restrict__ w,
                        const float* __restrict__ bias, float* __restrict__ h){
    __shared__ float ts[DTXT];
    const int b = blockIdx.y;
    const int n = blockIdx.x * 256 + threadIdx.x;
    for (int k = threadIdx.x; k < DTXT; k += 256) ts[k] = text[(size_t)b*DTXT + k];
    __syncthreads();
    float acc = 0.f;
    for (int k = 0; k < DTXT; k++) acc = fmaf(ts[k], w[(size_t)k*DIMG + n], acc);
    h[(size_t)b*DIMG + n] = gelu_f(acc + bias[n]);
}

__global__ void txt_fc2(const float* __restrict__ h, const float* __restrict__ w,
                        const float* __restrict__ bias, float* __restrict__ tq){
    __shared__ float ts[DIMG];
    const int b = blockIdx.y;
    const int n = blockIdx.x * 256 + threadIdx.x;
    for (int k = threadIdx.x; k < DIMG; k += 256) ts[k] = h[(size_t)b*DIMG + k];
    __syncthreads();
    float acc = 0.f;
    for (int k = 0; k < DIMG; k++) acc = fmaf(ts[k], w[(size_t)k*DIMG + n], acc);
    tq[(size_t)b*DIMG + n] = acc + bias[n];
}

__global__ void txt_ln(float* __restrict__ tq, const float* __restrict__ lw,
                       const float* __restrict__ lb){
    __shared__ float red[4];
    const int b = blockIdx.x, t = threadIdx.x;
    const int wv = t >> 6, lane = t & 63;
    float x[3];
    #pragma unroll
    for (int i = 0; i < 3; i++) x[i] = tq[(size_t)b*DIMG + t + i*256];
    float s = x[0] + x[1] + x[2];
    #pragma unroll
    for (int o = 1; o < 64; o <<= 1) s += __shfl_xor(s, o);
    if (lane == 0) red[wv] = s;
    __syncthreads();
    const float mu = (red[0]+red[1]+red[2]+red[3]) * (1.f/768.f);
    float q = 0.f;
    #pragma unroll
    for (int i = 0; i < 3; i++){ const float d = x[i]-mu; q = fmaf(d, d, q); }
    #pragma unroll
    for (int o = 1; o < 64; o <<= 1) q += __shfl_xor(q, o);
    __syncthreads();
    if (lane == 0) red[wv] = q;
    __syncthreads();
    const float var = (red[0]+red[1]+red[2]+red[3]) * (1.f/768.f);
    const float inv = rsqrtf(var + LN_EPS);
    #pragma unroll
    for (int i = 0; i < 3; i++){
        const int d = t + i*256;
        tq[(size_t)b*DIMG + d] = (x[i]-mu)*inv*lw[d] + lb[d];
    }
}

// --- prep: transpose+cast 768x768 weight --------------------------------
__global__ void prep_w(const float* __restrict__ w, bf16_t* __restrict__ wt){
    __shared__ float tile[32][33];
    const int r0 = blockIdx.y * 32, c0 = blockIdx.x * 32;
    const int tx = threadIdx.x, ty = threadIdx.y;
    #pragma unroll
    for (int i = 0; i < 4; i++)
        tile[ty + i*8][tx] = w[(size_t)(r0 + ty + i*8)*DIMG + c0 + tx];
    __syncthreads();
    #pragma unroll
    for (int i = 0; i < 4; i++)
        wt[(size_t)(c0 + ty + i*8)*DIMG + r0 + tx] = __float2bfloat16(tile[tx][ty + i*8]);
}

// --- u[b] = W2 @ tq[b] ----------------------------------------------------
__global__ void calc_u(const float* __restrict__ tq, const bf16_t* __restrict__ w2T,
                       float* __restrict__ u){
    __shared__ float ts[DIMG];
    const int b = blockIdx.y;
    const int n = blockIdx.x * 256 + threadIdx.x;
    for (int k = threadIdx.x; k < DIMG; k += 256) ts[k] = tq[(size_t)b*DIMG + k];
    __syncthreads();
    float acc = 0.f;
    for (int k = 0; k < DIMG; k++)
        acc = fmaf(ts[k], __bfloat162float(w2T[(size_t)k*DIMG + n]), acc);
    u[(size_t)b*DIMG + n] = acc;
}

// --- scale[row] = 1 + gamma*sigmoid(dimg + g_gcn*(h.u + b2.tq)) ----------
__global__ void scale_k(const bf16_t* __restrict__ h, const float* __restrict__ u,
                        const float* __restrict__ dimg, const float* __restrict__ b2,
                        const float* __restrict__ tq, const float* __restrict__ ggcn,
                        const float* __restrict__ gam, float* __restrict__ scale){
    const int gr = blockIdx.x * 4 + (threadIdx.x >> 6);
    const int lane = threadIdx.x & 63;
    if (gr >= MROWS) return;
    const int b = gr / NTOK;
    const bf16_t* hr = h + (size_t)gr*DIMG;
    const float* ub = u + (size_t)b*DIMG;
    const float* tb = tq + (size_t)b*DIMG;
    float s = 0.f;
    #pragma unroll
    for (int i = 0; i < 6; i++){
        const int d = i*128 + lane*2;
        const bf2_t hv = *(const bf2_t*)(hr + d);
        const float2 uv = *(const float2*)(ub + d);
        const float2 bv = *(const float2*)(b2 + d);
        const float2 tv = *(const float2*)(tb + d);
        s = fmaf(__bfloat162float(hv.x), uv.x, s);
        s = fmaf(__bfloat162float(hv.y), uv.y, s);
        s = fmaf(bv.x, tv.x, s);
        s = fmaf(bv.y, tv.y, s);
    }
    #pragma unroll
    for (int o = 1; o < 64; o <<= 1) s += __shfl_xor(s, o);
    const float dot = dimg[gr] + ggcn[0]*s;
    if (lane == 0)
        scale[gr] = 1.f + gam[0] / (1.f + expf(-dot));
}

// --- fused attention: S = X X^T/sqrt(D), softmax (exact), msg = P X ------
// grid (2, BATCH), 256 threads. Block handles 128 query rows of one batch.
__global__ __launch_bounds__(256, 2) void flash_attn(
    const bf16_t* __restrict__ xb, const bf16_t* __restrict__ xt,
    bf16_t* __restrict__ msg)
{
    __shared__ __align__(16) bf16_t Pl[128*LDP];   // 59.4 KB P in A-layout
    __shared__ __align__(16) bf16_t stage[64*136]; // 17.4 KB: S-stage/PV-stage/epilogue
    __shared__ float redm[2*128];
    __shared__ float reds[2*128];

    const int b  = blockIdx.y;
    const int m0 = blockIdx.x * 128;
    const int t    = threadIdx.x;
    const int lane = t & 63;
    const int wave = t >> 6;
    const int fr   = lane & 15;
    const int quad = lane >> 4;

    // ---------------- phase 1: S = X[m0:m0+128] @ X^T (128 x 256) --------
    const int wm = (wave & 1) * 64;     // S row offset within block
    const int wn = (wave >> 1) * 128;   // S col offset
    f32x4 acc[4][8];
    #pragma unroll
    for (int i = 0; i < 4; i++)
        #pragma unroll
        for (int j = 0; j < 8; j++)
            acc[i][j] = (f32x4){0.f,0.f,0.f,0.f};

    for (int k0 = 0; k0 < DIMG; k0 += 32){
        __syncthreads();
        #pragma unroll
        for (int s = 0; s < 4; s++){
            const int idx = t + s*256;            // 1024 x 16B = 16 KB
            const int row = idx >> 2, off = (idx & 3) * 8;
            __builtin_amdgcn_global_load_lds(
                (gvoid_t*)(xb + ((size_t)b*PN + row)*DIMG + k0 + off),
                (lvoid_t*)(stage + idx*8), 16, 0, 0);
        }
        __syncthreads();
        #pragma unroll
        for (int jh = 0; jh < 2; jh++){
            bf16x8 fa[4], fb[4];
            #pragma unroll
            for (int i = 0; i < 4; i++){
                fa[i] = *(const bf16x8*)(stage + (m0 + wm + i*16 + fr)*32 + quad*8);
                fb[i] = *(const bf16x8*)(stage + (wn + (jh*4 + i)*16 + fr)*32 + quad*8);
            }
            #pragma unroll
            for (int i = 0; i < 4; i++)
                #pragma unroll
                for (int j = 0; j < 4; j++)
                    acc[i][jh*4 + j] = __builtin_amdgcn_mfma_f32_16x16x32_bf16(
                        fa[i], fb[j], acc[i][jh*4 + j], 0, 0, 0);
        }
    }

    // ---------------- softmax (exact, rows of 256 padded to 196 valid) ---
    const float sscale = 0.03608439182435161256f;  // 1/sqrt(768)
    const int wi = wn >> 7;                         // 0 or 1
    float mx[4][4];
    #pragma unroll
    for (int i = 0; i < 4; i++)
        #pragma unroll
        for (int r = 0; r < 4; r++){
            float m_ = -3e38f;
            #pragma unroll
            for (int j = 0; j < 8; j++){
                const bool ok = (wn == 0) || (j*16 + fr < NTOK - 128);
                if (ok) m_ = fmaxf(m_, acc[i][j][r]*sscale);
            }
            #pragma unroll
            for (int o = 1; o < 16; o <<= 1) m_ = fmaxf(m_, __shfl_xor(m_, o));
            mx[i][r] = m_;
            if (fr == 0) redm[wi*128 + wm + i*16 + quad*4 + r] = m_;
        }
    __syncthreads();
    float sm[4][4];
    #pragma unroll
    for (int i = 0; i < 4; i++)
        #pragma unroll
        for (int r = 0; r < 4; r++){
            const int row = wm + i*16 + quad*4 + r;
            const float mxf = fmaxf(redm[row], redm[128 + row]);
            float s_ = 0.f;
            #pragma unroll
            for (int j = 0; j < 8; j++){
                const bool ok = (wn == 0) || (j*16 + fr < NTOK - 128);
                const float p = ok ? __expf(acc[i][j][r]*sscale - mxf) : 0.f;
                acc[i][j][r] = p;
                s_ += p;
            }
            #pragma unroll
            for (int o = 1; o < 16; o <<= 1) s_ += __shfl_xor(s_, o);
            if (fr == 0) reds[wi*128 + row] = s_;
        }
    __syncthreads();
    #pragma unroll
    for (int i = 0; i < 4; i++)
        #pragma unroll
        for (int r = 0; r < 4; r++){
            const int row = wm + i*16 + quad*4 + r;
            const float inv = 1.f / (reds[row] + reds[128 + row]);
            #pragma unroll
            for (int j = 0; j < 8; j++){
                const int col = wn + j*16 + fr;
                if (col < LDP)
                    Pl[row*LDP + col] = __float2bfloat16(acc[i][j][r] * inv);
            }
        }
    __syncthreads();

    // ---------------- phase 2: msg[m0:m0+128] = P @ X (K = 224) ----------
    const int wm2 = (wave & 1) * 64;
    const int wn2 = (wave >> 1) * 64;
    for (int nt = 0; nt < 6; nt++){
        const int n0 = nt * 128;
        f32x4 acc2[4][4];
        #pragma unroll
        for (int i = 0; i < 4; i++)
            #pragma unroll
            for (int j = 0; j < 4; j++)
                acc2[i][j] = (f32x4){0.f,0.f,0.f,0.f};

        for (int k0 = 0; k0 < FK; k0 += 32){
            __syncthreads();
            #pragma unroll
            for (int s = 0; s < 2; s++){
                const int idx = t + s*256;        // 512 x 16B = 8 KB
                const int row = idx >> 2, off = (idx & 3) * 8;
                __builtin_amdgcn_global_load_lds(
                    (gvoid_t*)(xt + ((size_t)b*DIMG + n0 + row)*PN + k0 + off),
                    (lvoid_t*)(stage + idx*8), 16, 0, 0);
            }
            __syncthreads();
            bf16x8 fa[4], fb[4];
            #pragma unroll
            for (int i = 0; i < 4; i++){
                fa[i] = *(const bf16x8*)(Pl + (wm2 + i*16 + fr)*LDP + k0 + quad*8);
                fb[i] = *(const bf16x8*)(stage + (wn2 + i*16 + fr)*32 + quad*8);
            }
            #pragma unroll
            for (int i = 0; i < 4; i++)
                #pragma unroll
                for (int j = 0; j < 4; j++)
                    acc2[i][j] = __builtin_amdgcn_mfma_f32_16x16x32_bf16(
                        fa[i], fb[j], acc2[i][j], 0, 0, 0);
        }

        // epilogue: 2 chunks of 64 rows via LDS, coalesced bf16x8 stores
        #pragma unroll
        for (int c = 0; c < 2; c++){
            __syncthreads();
            if (wm2 == c*64){
                #pragma unroll
                for (int i = 0; i < 4; i++)
                    #pragma unroll
                    for (int j = 0; j < 4; j++)
                        #pragma unroll
                        for (int r = 0; r < 4; r++)
                            stage[(i*16 + quad*4 + r)*136 + wn2 + j*16 + fr] =
                                __float2bfloat16(acc2[i][j][r]);
            }
            __syncthreads();
            const int lr = t >> 2;
            const int grow = m0 + c*64 + lr;
            if (grow < NTOK){
                const int col0 = (t & 3) * 32;
                bf16_t* dst = msg + ((size_t)b*NTOK + grow)*DIMG + n0 + col0;
                const bf16_t* srcp = stage + lr*136 + col0;
                #pragma unroll
                for (int u2 = 0; u2 < 4; u2++)
                    *(uint4*)(dst + u2*8) = *(const uint4*)(srcp + u2*8);
            }
        }
    }
}

// --- MFMA GEMM with LDS-staged vectorized epilogue (modes 2,3 only) ------
// MODE 2: bf16 h = gelu(C+bias)     MODE 3: fp32 out = (res + g*(C+bias))*scale
template<int MODE>
__global__ __launch_bounds__(256) void gemm_bt(
    const bf16_t* __restrict__ Aall, const bf16_t* __restrict__ Btall,
    int lda, int ldb, int K,
    float* __restrict__ outF, bf16_t* __restrict__ outB,
    const float* __restrict__ bias, const float* __restrict__ res,
    const float* __restrict__ gscal, const float* __restrict__ scale)
{
    __shared__ __align__(16) union {
        struct { bf16_t a[128*32]; bf16_t b[128*32]; } s;
        float ep[32*132];
    } sm;
    const int m0 = blockIdx.y * 128;
    const int n0 = blockIdx.x * 128;

    const int t    = threadIdx.x;
    const int lane = t & 63;
    const int wave = t >> 6;
    const int wm   = (wave & 1) * 64;
    const int wn   = (wave >> 1) * 64;
    const int fr   = lane & 15;
    const int quad = lane >> 4;

    f32x4 acc[4][4];
    #pragma unroll
    for (int i = 0; i < 4; i++)
        #pragma unroll
        for (int j = 0; j < 4; j++)
            acc[i][j] = (f32x4){0.f, 0.f, 0.f, 0.f};

    const int lin0 = t, lin1 = t + 256;
    const int r0 = lin0 >> 2, s0 = (lin0 & 3) * 8;
    const int r1 = lin1 >> 2, s1 = (lin1 & 3) * 8;

    for (int k0 = 0; k0 < K; k0 += 32){
        __syncthreads();
        __builtin_amdgcn_global_load_lds((gvoid_t*)(Aall + (size_t)(m0+r0)*lda + k0 + s0),
                                         (lvoid_t*)(sm.s.a + lin0*8), 16, 0, 0);
        __builtin_amdgcn_global_load_lds((gvoid_t*)(Aall + (size_t)(m0+r1)*lda + k0 + s1),
                                         (lvoid_t*)(sm.s.a + lin1*8), 16, 0, 0);
        __builtin_amdgcn_global_load_lds((gvoid_t*)(Btall + (size_t)(n0+r0)*ldb + k0 + s0),
                                         (lvoid_t*)(sm.s.b + lin0*8), 16, 0, 0);
        __builtin_amdgcn_global_load_lds((gvoid_t*)(Btall + (size_t)(n0+r1)*ldb + k0 + s1),
                                         (lvoid_t*)(sm.s.b + lin1*8), 16, 0, 0);
        __syncthreads();
        bf16x8 fa[4], fb[4];
        #pragma unroll
        for (int i = 0; i < 4; i++){
            fa[i] = *(const bf16x8*)(sm.s.a + (wm + i*16 + fr)*32 + quad*8);
            fb[i] = *(const bf16x8*)(sm.s.b + (wn + i*16 + fr)*32 + quad*8);
        }
        #pragma unroll
        for (int i = 0; i < 4; i++)
            #pragma unroll
            for (int j = 0; j < 4; j++)
                acc[i][j] = __builtin_amdgcn_mfma_f32_16x16x32_bf16(fa[i], fb[j], acc[i][j], 0, 0, 0);
    }

    const float g = (MODE == 3) ? gscal[0] : 0.f;
    const int lr = t >> 3;
    const int cs = (t & 7) * 16;
    #pragma unroll
    for (int c = 0; c < 4; c++){
        __syncthreads();
        if ((wm == 0) == (c < 2)){
            const int ib = (c & 1) * 2;
            #pragma unroll
            for (int ii = 0; ii < 2; ii++)
                #pragma unroll
                for (int j = 0; j < 4; j++)
                    #pragma unroll
                    for (int r = 0; r < 4; r++)
                        sm.ep[(ii*16 + quad*4 + r)*132 + wn + j*16 + fr] = acc[ib+ii][j][r];
        }
        __syncthreads();
        const int grow = m0 + c*32 + lr;
        float4 v[4];
        const float4* vp = (const float4*)(sm.ep + lr*132 + cs);
        #pragma unroll
        for (int k = 0; k < 4; k++) v[k] = vp[k];

        if (MODE == 2){
            const float4* bp = (const float4*)(bias + n0 + cs);
            bf16_t tmp[16];
            #pragma unroll
            for (int k = 0; k < 4; k++){
                const float4 bv = bp[k];
                tmp[4*k+0] = __float2bfloat16(gelu_f(v[k].x + bv.x));
                tmp[4*k+1] = __float2bfloat16(gelu_f(v[k].y + bv.y));
                tmp[4*k+2] = __float2bfloat16(gelu_f(v[k].z + bv.z));
                tmp[4*k+3] = __float2bfloat16(gelu_f(v[k].w + bv.w));
            }
            float4* dp = (float4*)(outB + (size_t)grow*DIMG + n0 + cs);
            dp[0] = ((float4*)tmp)[0];
            dp[1] = ((float4*)tmp)[1];
        } else {
            const int bb = grow / NTOK;
            const int nn = grow - bb*NTOK;
            const size_t off = ((size_t)bb*197 + 1 + nn)*DIMG + n0 + cs;
            const float sc = scale[grow];
            const float4* bp = (const float4*)(bias + n0 + cs);
            const float4* rp = (const float4*)(res + off);
            float4* dp = (float4*)(outF + off);
            #pragma unroll
            for (int k = 0; k < 4; k++){
                const float4 bv = bp[k];
                const float4 rv = rp[k];
                float4 o;
                o.x = (rv.x + g*(v[k].x + bv.x)) * sc;
                o.y = (rv.y + g*(v[k].y + bv.y)) * sc;
                o.z = (rv.z + g*(v[k].z + bv.z)) * sc;
                o.w = (rv.w + g*(v[k].w + bv.w)) * sc;
                dp[k] = o;
            }
        }
    }
}

extern "C" void kernel_launch(void* const* d_in, const int* in_sizes, int n_in,
                              void* d_out, int out_size, void* d_ws, size_t ws_size,
                              hipStream_t stream){
    (void)in_sizes; (void)n_in; (void)out_size;
    const float* img  = (const float*)d_in[0];
    const float* text = (const float*)d_in[1];
    const float* w1m  = (const float*)d_in[2];
    const float* b1m  = (const float*)d_in[3];
    const float* w2m  = (const float*)d_in[4];
    const float* b2m  = (const float*)d_in[5];
    const float* ggcn = (const float*)d_in[6];
    const float* w1t  = (const float*)d_in[7];
    const float* b1t  = (const float*)d_in[8];
    const float* w2t  = (const float*)d_in[9];
    const float* b2t  = (const float*)d_in[10];
    const float* lnw  = (const float*)d_in[11];
    const float* lnb  = (const float*)d_in[12];
    const float* gam  = (const float*)d_in[13];
    float* out = (float*)d_out;

    char* p = (char*)d_ws;
    auto alloc = [&](size_t n){ void* r = (void*)p; p += (n + 255) & ~(size_t)255; return r; };
    bf16_t* x_bf   = (bf16_t*)alloc((size_t)BATCH*PN*DIMG*2);
    bf16_t* xT_bf  = (bf16_t*)alloc((size_t)BATCH*DIMG*PN*2);
    bf16_t* msg_bf = (bf16_t*)alloc((size_t)MROWS*DIMG*2);
    bf16_t* h_bf   = (bf16_t*)alloc((size_t)MROWS*DIMG*2);
    bf16_t* w1T    = (bf16_t*)alloc((size_t)DIMG*DIMG*2);
    bf16_t* w2T    = (bf16_t*)alloc((size_t)DIMG*DIMG*2);
    float*  htxt   = (float*) alloc((size_t)BATCH*DIMG*4);
    float*  tq     = (float*) alloc((size_t)BATCH*DIMG*4);
    float*  u      = (float*) alloc((size_t)BATCH*DIMG*4);
    float*  dimg   = (float*) alloc((size_t)MROWS*4);
    float*  scl    = (float*) alloc((size_t)MROWS*4);
    if ((size_t)(p - (char*)d_ws) > ws_size) return;

    // text branch (prep_row consumes tq)
    txt_fc1<<<dim3(3, BATCH), dim3(256), 0, stream>>>(text, w1t, b1t, htxt);
    txt_fc2<<<dim3(3, BATCH), dim3(256), 0, stream>>>(htxt, w2t, b2t, tq);
    txt_ln<<<dim3(BATCH), dim3(256), 0, stream>>>(tq, lnw, lnb);

    prep_w<<<dim3(24, 24), dim3(32, 8), 0, stream>>>(w1m, w1T);
    prep_w<<<dim3(24, 24), dim3(32, 8), 0, stream>>>(w2m, w2T);
    calc_u<<<dim3(3, BATCH), dim3(256), 0, stream>>>(tq, w2T, u);
    prep_row<<<dim3(BATCH*PN/4), dim3(256), 0, stream>>>(img, tq, x_bf, dimg);
    prep_xt<<<dim3(12, 4, BATCH), dim3(32, 8), 0, stream>>>(x_bf, xT_bf);
    cls_copy<<<dim3(768), dim3(256), 0, stream>>>(img, out);

    // fused attention: S -> softmax -> msg, no S/A in HBM
    flash_attn<<<dim3(2, BATCH), dim3(256), 0, stream>>>(x_bf, xT_bf, msg_bf);

    // G3: h = gelu(msg @ w1 + b1)
    gemm_bt<2><<<dim3(6, 392), dim3(256), 0, stream>>>(
        msg_bf, w1T, DIMG, DIMG, DIMG, nullptr, h_bf, b1m, nullptr, nullptr, nullptr);
    // scale = 1 + gam*sigmoid(img.tq + g*(h.u + b2.tq))
    scale_k<<<dim3(MROWS/4), dim3(256), 0, stream>>>(h_bf, u, dimg, b2m, tq, ggcn, gam, scl);
    // G4: out rows = (img + g*(h @ w2 + b2)) * scale
    gemm_bt<3><<<dim3(6, 392), dim3(256), 0, stream>>>(
        h_bf, w2T, DIMG, DIMG, DIMG, out, nullptr, b2m, img, ggcn, scl);
}